// Round 2
// baseline (2106.365 us; speedup 1.0000x reference)
//
#include <hip/hip_runtime.h>
#include <math.h>

#define NPTS 8192
#define NB 2
#define NCH 4
#define CSZ 2048
#define DF 64
#define HID 128
#define OUTC 64
#define KNN 16

// ---------------- top-k sorted insert (ascending d, stable = lowest index wins on ties)
template<int K>
__device__ __forceinline__ void topk_insert(float (&d)[K], int (&id)[K], float nd, int ni) {
#pragma unroll
  for (int i = K - 1; i >= 1; --i) {
    bool sh = nd < d[i - 1];
    bool he = nd < d[i];
    d[i]  = sh ? d[i - 1]  : (he ? nd : d[i]);
    id[i] = sh ? id[i - 1] : (he ? ni : id[i]);
  }
  bool h0 = nd < d[0];
  d[0]  = h0 ? nd : d[0];
  id[0] = h0 ? ni : id[0];
}

// ---------------- prep: pack points as float4(x,y,z,0)
__global__ void k_prep(const float* __restrict__ xyz1, const float* __restrict__ xyz2,
                       const float* __restrict__ flow1,
                       float4* __restrict__ A, float4* __restrict__ Bq, float4* __restrict__ Qx) {
  int t = blockIdx.x * 256 + threadIdx.x;      // 0..16383
  int b = t >> 13, n = t & (NPTS - 1);
  size_t base = (size_t)b * 3 * NPTS + n;
  float x1 = xyz1[base], y1 = xyz1[base + NPTS], z1 = xyz1[base + 2 * NPTS];
  float fx = flow1[base], fy = flow1[base + NPTS], fz = flow1[base + 2 * NPTS];
  float sx = x1 + fx, sy = y1 + fy, sz = z1 + fz;
  A[t]  = make_float4(sx, sy, sz, 0.f);
  Bq[t] = make_float4(x1, y1, z1, 0.f);
  float x2 = xyz2[base], y2 = xyz2[base + NPTS], z2 = xyz2[base + 2 * NPTS];
  Qx[t] = make_float4(x2, y2, z2, 0.f);
}

// ---------------- feat2 [B,D,N] -> F [B,N,D]
__global__ void k_feat_T(const float* __restrict__ feat2, float* __restrict__ F) {
  __shared__ float t[64][65];
  int b = blockIdx.y;
  int n0 = blockIdx.x * 64;
  int l = threadIdx.x & 63, w = threadIdx.x >> 6;
#pragma unroll
  for (int it = 0; it < 16; ++it) {
    int dd = w + it * 4;
    t[dd][l] = feat2[((size_t)b * DF + dd) * NPTS + n0 + l];
  }
  __syncthreads();
#pragma unroll
  for (int it = 0; it < 16; ++it) {
    int nn = w + it * 4;
    F[((size_t)b * NPTS + n0 + nn) * DF + l] = t[l][nn];
  }
}

// ---------------- brute-force KNN over one chunk of the database
// distance = (qx-px)^2+(qy-py)^2+(qz-pz)^2  (difference form: rel err ~eps,
// ordering matches the f64 numpy reference except true ties)
template<int K>
__global__ void k_knn_partial(const float4* __restrict__ db, const float4* __restrict__ qry,
                              float* __restrict__ Ed, int* __restrict__ Ei) {
  __shared__ float4 tile[CSZ];
  int qg = blockIdx.x * 256 + threadIdx.x;     // global query
  int b = qg >> 13;
  int chunk = blockIdx.y;
  int dbase = b * NPTS + chunk * CSZ;
  for (int j = threadIdx.x; j < CSZ; j += 256) tile[j] = db[dbase + j];
  __syncthreads();
  float4 q = qry[qg];
  float d[K]; int id[K];
#pragma unroll
  for (int i = 0; i < K; ++i) { d[i] = __builtin_inff(); id[i] = 0; }
  int ibase = chunk * CSZ;
  for (int j = 0; j < CSZ; ++j) {
    float4 p = tile[j];
    float dx = q.x - p.x, dy = q.y - p.y, dz = q.z - p.z;
    float dist = fmaf(dx, dx, fmaf(dy, dy, dz * dz));
    if (dist < d[K - 1]) topk_insert<K>(d, id, dist, ibase + j);
  }
  int eb = (qg * NCH + chunk) * K;
#pragma unroll
  for (int i = 0; i < K; ++i) { Ed[eb + i] = d[i]; Ei[eb + i] = id[i]; }
}

// ---------------- merge 4 sorted 16-lists -> final 16 indices
__global__ void k_merge16(const float* __restrict__ Ed, const int* __restrict__ Ei,
                          int* __restrict__ Didx) {
  int q = blockIdx.x * 256 + threadIdx.x;
  int eb = q * NCH * KNN;
  int p0 = 0, p1 = 0, p2 = 0, p3 = 0;
  for (int r = 0; r < KNN; ++r) {
    float bd = __builtin_inff(); int bi = 0x7fffffff; int bc = 0;
    if (p0 < KNN) { float dc = Ed[eb + p0];            int ic = Ei[eb + p0];            if (dc < bd || (dc == bd && ic < bi)) { bd = dc; bi = ic; bc = 0; } }
    if (p1 < KNN) { float dc = Ed[eb + KNN + p1];      int ic = Ei[eb + KNN + p1];      if (dc < bd || (dc == bd && ic < bi)) { bd = dc; bi = ic; bc = 1; } }
    if (p2 < KNN) { float dc = Ed[eb + 2 * KNN + p2];  int ic = Ei[eb + 2 * KNN + p2];  if (dc < bd || (dc == bd && ic < bi)) { bd = dc; bi = ic; bc = 2; } }
    if (p3 < KNN) { float dc = Ed[eb + 3 * KNN + p3];  int ic = Ei[eb + 3 * KNN + p3];  if (dc < bd || (dc == bd && ic < bi)) { bd = dc; bi = ic; bc = 3; } }
    Didx[q * KNN + r] = bi;
    p0 += (bc == 0); p1 += (bc == 1); p2 += (bc == 2); p3 += (bc == 3);
  }
}

// ---------------- merge 4 sorted 3-lists + inverse-distance warp interpolation
__global__ void k_knn3_finish(const float* __restrict__ Ed, const int* __restrict__ Ei,
                              const float4* __restrict__ A, const float4* __restrict__ Qx,
                              const float* __restrict__ flow1, float* __restrict__ out1,
                              float4* __restrict__ C) {
  int qg = blockIdx.x * 256 + threadIdx.x;
  int b = qg >> 13, n = qg & (NPTS - 1);
  int eb = qg * NCH * 3;
  int p0 = 0, p1 = 0, p2 = 0, p3 = 0;
  int idx[3];
#pragma unroll
  for (int r = 0; r < 3; ++r) {
    float bd = __builtin_inff(); int bi = 0x7fffffff; int bc = 0;
    if (p0 < 3) { float dc = Ed[eb + p0];         int ic = Ei[eb + p0];         if (dc < bd || (dc == bd && ic < bi)) { bd = dc; bi = ic; bc = 0; } }
    if (p1 < 3) { float dc = Ed[eb + 3 + p1];     int ic = Ei[eb + 3 + p1];     if (dc < bd || (dc == bd && ic < bi)) { bd = dc; bi = ic; bc = 1; } }
    if (p2 < 3) { float dc = Ed[eb + 6 + p2];     int ic = Ei[eb + 6 + p2];     if (dc < bd || (dc == bd && ic < bi)) { bd = dc; bi = ic; bc = 2; } }
    if (p3 < 3) { float dc = Ed[eb + 9 + p3];     int ic = Ei[eb + 9 + p3];     if (dc < bd || (dc == bd && ic < bi)) { bd = dc; bi = ic; bc = 3; } }
    idx[r] = bi;
    p0 += (bc == 0); p1 += (bc == 1); p2 += (bc == 2); p3 += (bc == 3);
  }
  float4 q = Qx[qg];
  float ivd[3];
  float s = 0.f;
#pragma unroll
  for (int r = 0; r < 3; ++r) {
    float4 p = A[b * NPTS + idx[r]];
    float gx = p.x - q.x, gy = p.y - q.y, gz = p.z - q.z;
    float dist = sqrtf(gx * gx + gy * gy + gz * gz);
    dist = fmaxf(dist, 1e-10f);
    ivd[r] = 1.0f / dist;
    s += ivd[r];
  }
  float w0 = ivd[0] / s, w1 = ivd[1] / s, w2 = ivd[2] / s;
  size_t fb = (size_t)b * 3 * NPTS;
  float f2x = w0 * flow1[fb + idx[0]]            + w1 * flow1[fb + idx[1]]            + w2 * flow1[fb + idx[2]];
  float f2y = w0 * flow1[fb + NPTS + idx[0]]     + w1 * flow1[fb + NPTS + idx[1]]     + w2 * flow1[fb + NPTS + idx[2]];
  float f2z = w0 * flow1[fb + 2 * NPTS + idx[0]] + w1 * flow1[fb + 2 * NPTS + idx[1]] + w2 * flow1[fb + 2 * NPTS + idx[2]];
  float wx = q.x - f2x, wy = q.y - f2y, wz = q.z - f2z;
  out1[fb + n] = wx;
  out1[fb + NPTS + n] = wy;
  out1[fb + 2 * NPTS + n] = wz;
  C[qg] = make_float4(wx, wy, wz, 0.f);
}

// ---------------- gather + MLP(67->128->64) + leaky + max over K
__global__ void __launch_bounds__(256) k_mlp(const int* __restrict__ Didx, const float4* __restrict__ C,
                                             const float4* __restrict__ Bq, const float* __restrict__ F,
                                             const float* __restrict__ W1, const float* __restrict__ b1,
                                             const float* __restrict__ W2, const float* __restrict__ b2,
                                             float* __restrict__ out0) {
  int gid = blockIdx.x * 256 + threadIdx.x;   // 262144 threads
  int q = gid >> 4, k = gid & 15;
  int b = q >> 13, n = q & (NPTS - 1);
  int idx = Didx[q * KNN + k];
  float4 wp = C[b * NPTS + idx];
  float4 qp = Bq[q];
  float x[3 + DF];
  x[0] = wp.x - qp.x; x[1] = wp.y - qp.y; x[2] = wp.z - qp.z;
  const float4* fp = (const float4*)(F + ((size_t)(b * NPTS + idx)) * DF);
#pragma unroll
  for (int j = 0; j < DF / 4; ++j) {
    float4 v = fp[j];
    x[3 + 4 * j] = v.x; x[4 + 4 * j] = v.y; x[5 + 4 * j] = v.z; x[6 + 4 * j] = v.w;
  }
  float acc[OUTC];
#pragma unroll
  for (int o = 0; o < OUTC; ++o) acc[o] = b2[o];
  // fused layer1/layer2 in h-tiles of 16 (all register arrays statically indexed)
  for (int ht = 0; ht < HID / 16; ++ht) {
    float h1t[16];
#pragma unroll
    for (int hh = 0; hh < 16; ++hh) {
      int h = ht * 16 + hh;
      const float* wr = W1 + h * (3 + DF);
      float a = b1[h];
#pragma unroll
      for (int c = 0; c < 3 + DF; ++c) a = fmaf(x[c], wr[c], a);
      h1t[hh] = a >= 0.f ? a : 0.1f * a;
    }
#pragma unroll
    for (int o = 0; o < OUTC; ++o) {
      const float* wr = W2 + o * HID + ht * 16;
      float a = acc[o];
#pragma unroll
      for (int hh = 0; hh < 16; ++hh) a = fmaf(h1t[hh], wr[hh], a);
      acc[o] = a;
    }
  }
  int obase = (b * OUTC) * NPTS + n;
#pragma unroll
  for (int o = 0; o < OUTC; ++o) {
    float a = acc[o];
    a = a >= 0.f ? a : 0.1f * a;
    float m = a;
    m = fmaxf(m, __shfl_xor(m, 1));
    m = fmaxf(m, __shfl_xor(m, 2));
    m = fmaxf(m, __shfl_xor(m, 4));
    m = fmaxf(m, __shfl_xor(m, 8));
    if (k == 0) out0[obase + o * NPTS] = m;
  }
}

extern "C" void kernel_launch(void* const* d_in, const int* in_sizes, int n_in,
                              void* d_out, int out_size, void* d_ws, size_t ws_size,
                              hipStream_t stream) {
  const float* xyz1  = (const float*)d_in[0];
  const float* xyz2  = (const float*)d_in[1];
  const float* flow1 = (const float*)d_in[2];
  const float* feat2 = (const float*)d_in[3];
  const float* W1    = (const float*)d_in[4];
  const float* b1    = (const float*)d_in[5];
  const float* W2    = (const float*)d_in[6];
  const float* b2    = (const float*)d_in[7];
  float* out0 = (float*)d_out;
  float* out1 = out0 + (size_t)NB * OUTC * NPTS;

  float* w = (float*)d_ws;
  float4* A    = (float4*)(w);             // 16384 float4 = 65536 f
  float4* Bq   = (float4*)(w + 65536);
  float4* Qx   = (float4*)(w + 131072);
  float4* Cw   = (float4*)(w + 196608);
  float*  F    = w + 262144;               // 1048576 f
  float*  Ed3  = w + 1310720;              // 196608 f
  int*    Ei3  = (int*)(w + 1507328);
  float*  Ed16 = w + 1703936;              // 1048576 f
  int*    Ei16 = (int*)(w + 2752512);
  int*    Didx = (int*)(w + 3801088);      // 262144 ints

  k_prep<<<64, 256, 0, stream>>>(xyz1, xyz2, flow1, A, Bq, Qx);
  k_feat_T<<<dim3(128, 2), 256, 0, stream>>>(feat2, F);
  k_knn_partial<3><<<dim3(64, NCH), 256, 0, stream>>>(A, Qx, Ed3, Ei3);
  k_knn3_finish<<<64, 256, 0, stream>>>(Ed3, Ei3, A, Qx, flow1, out1, Cw);
  k_knn_partial<16><<<dim3(64, NCH), 256, 0, stream>>>(Cw, Bq, Ed16, Ei16);
  k_merge16<<<64, 256, 0, stream>>>(Ed16, Ei16, Didx);
  k_mlp<<<1024, 256, 0, stream>>>(Didx, Cw, Bq, F, W1, b1, W2, b2, out0);
}

// Round 6
// 1146.635 us; speedup vs baseline: 1.8370x; 1.8370x over previous
//
#include <hip/hip_runtime.h>
#include <math.h>

#define NPTS 8192
#define NB 2
#define DF 64
#define HID 128
#define OUTC 64
#define KNN 16

// ---------------- prep: pack points as float4(x,y,z,0)
__global__ void k_prep(const float* __restrict__ xyz1, const float* __restrict__ xyz2,
                       const float* __restrict__ flow1,
                       float4* __restrict__ A, float4* __restrict__ Bq, float4* __restrict__ Qx) {
  int t = blockIdx.x * 256 + threadIdx.x;      // 0..16383
  int b = t >> 13, n = t & (NPTS - 1);
  size_t base = (size_t)b * 3 * NPTS + n;
  float x1 = xyz1[base], y1 = xyz1[base + NPTS], z1 = xyz1[base + 2 * NPTS];
  float fx = flow1[base], fy = flow1[base + NPTS], fz = flow1[base + 2 * NPTS];
  float sx = x1 + fx, sy = y1 + fy, sz = z1 + fz;
  A[t]  = make_float4(sx, sy, sz, 0.f);
  Bq[t] = make_float4(x1, y1, z1, 0.f);
  float x2 = xyz2[base], y2 = xyz2[base + NPTS], z2 = xyz2[base + 2 * NPTS];
  Qx[t] = make_float4(x2, y2, z2, 0.f);
}

// ---------------- feat2 [B,D,N] -> F [B,N,D]
__global__ void k_feat_T(const float* __restrict__ feat2, float* __restrict__ F) {
  __shared__ float t[64][65];
  int b = blockIdx.y;
  int n0 = blockIdx.x * 64;
  int l = threadIdx.x & 63, w = threadIdx.x >> 6;
#pragma unroll
  for (int it = 0; it < 16; ++it) {
    int dd = w + it * 4;
    t[dd][l] = feat2[((size_t)b * DF + dd) * NPTS + n0 + l];
  }
  __syncthreads();
#pragma unroll
  for (int it = 0; it < 16; ++it) {
    int nn = w + it * 4;
    F[((size_t)b * NPTS + n0 + nn) * DF + l] = t[l][nn];
  }
}

// ---------------- pad W1 [128][67] -> W1p [128][68] (col 67 = 0), rows 16B-aligned
__global__ void k_padw1(const float* __restrict__ W1, float* __restrict__ W1p) {
  int t = blockIdx.x * 256 + threadIdx.x;
  if (t >= 128 * 68) return;
  int h = t / 68, c = t - h * 68;
  W1p[t] = (c < 67) ? W1[h * 67 + c] : 0.f;
}

// ---------------- wave-per-2-queries exact KNN, lane-distributed sorted top-K
// List lives across lanes: lane l holds the l-th smallest (d, idx) seen so far.
// Candidates filtered by exact (d,idx) compare vs the K-th element; inserts are
// wave-wide shuffle shifts (processed in ascending point index for tie order).
template<int K>
__global__ void __launch_bounds__(256) k_knn_wave(const float4* __restrict__ db,
                                                  const float4* __restrict__ qry,
                                                  int* __restrict__ outIdx) {
  int wid = (blockIdx.x * 256 + threadIdx.x) >> 6;   // 0..8191
  int lane = threadIdx.x & 63;
  int b = wid >> 12;                                  // batch
  int q0 = wid * 2, q1 = wid * 2 + 1;
  float4 Q0 = qry[q0], Q1 = qry[q1];
  const float4* base = db + (size_t)b * NPTS;

  float ld0 = __builtin_inff(), ld1 = __builtin_inff();
  int   li0 = 0x7fffffff,       li1 = 0x7fffffff;
  float cap0 = __builtin_inff(), cap1 = __builtin_inff();
  int   ci0 = 0x7fffffff,        ci1 = 0x7fffffff;

  for (int t = 0; t < NPTS / 64; ++t) {
    int j = t * 64 + lane;
    float4 p = base[j];
    float ax = Q0.x - p.x, ay = Q0.y - p.y, az = Q0.z - p.z;
    float d0 = fmaf(ax, ax, fmaf(ay, ay, az * az));
    float bx = Q1.x - p.x, by = Q1.y - p.y, bz = Q1.z - p.z;
    float d1 = fmaf(bx, bx, fmaf(by, by, bz * bz));

    unsigned long long m0 = __ballot((d0 < cap0) || (d0 == cap0 && j < ci0));
    if (m0) {
      do {
        int c = __ffsll(m0) - 1; m0 &= m0 - 1;
        float bd = __shfl(d0, c); int bi = t * 64 + c;
        bool pred = (ld0 > bd) || (ld0 == bd && li0 > bi);
        float sld = __shfl_up(ld0, 1);
        int   sli = __shfl_up(li0, 1);
        int   ppr = __shfl_up((int)pred, 1);
        bool  pp = (lane > 0) && ppr;
        ld0 = pred ? (pp ? sld : bd) : ld0;
        li0 = pred ? (pp ? sli : bi) : li0;
      } while (m0);
      cap0 = __shfl(ld0, K - 1); ci0 = __shfl(li0, K - 1);
    }
    unsigned long long m1 = __ballot((d1 < cap1) || (d1 == cap1 && j < ci1));
    if (m1) {
      do {
        int c = __ffsll(m1) - 1; m1 &= m1 - 1;
        float bd = __shfl(d1, c); int bi = t * 64 + c;
        bool pred = (ld1 > bd) || (ld1 == bd && li1 > bi);
        float sld = __shfl_up(ld1, 1);
        int   sli = __shfl_up(li1, 1);
        int   ppr = __shfl_up((int)pred, 1);
        bool  pp = (lane > 0) && ppr;
        ld1 = pred ? (pp ? sld : bd) : ld1;
        li1 = pred ? (pp ? sli : bi) : li1;
      } while (m1);
      cap1 = __shfl(ld1, K - 1); ci1 = __shfl(li1, K - 1);
    }
  }
  if (lane < K) {
    outIdx[q0 * K + lane] = li0;
    outIdx[q1 * K + lane] = li1;
  }
}

// ---------------- 3-NN inverse-distance warp interpolation (indices precomputed)
__global__ void k_warp_finish(const int* __restrict__ idx3,
                              const float4* __restrict__ A, const float4* __restrict__ Qx,
                              const float* __restrict__ flow1, float* __restrict__ out1,
                              float4* __restrict__ C) {
  int qg = blockIdx.x * 256 + threadIdx.x;
  int b = qg >> 13, n = qg & (NPTS - 1);
  int idx[3];
#pragma unroll
  for (int r = 0; r < 3; ++r) idx[r] = idx3[qg * 3 + r];
  float4 q = Qx[qg];
  float ivd[3];
  float s = 0.f;
#pragma unroll
  for (int r = 0; r < 3; ++r) {
    float4 p = A[b * NPTS + idx[r]];
    float gx = p.x - q.x, gy = p.y - q.y, gz = p.z - q.z;
    float dist = sqrtf(gx * gx + gy * gy + gz * gz);
    dist = fmaxf(dist, 1e-10f);
    ivd[r] = 1.0f / dist;
    s += ivd[r];
  }
  float w0 = ivd[0] / s, w1 = ivd[1] / s, w2 = ivd[2] / s;
  size_t fb = (size_t)b * 3 * NPTS;
  float f2x = w0 * flow1[fb + idx[0]]            + w1 * flow1[fb + idx[1]]            + w2 * flow1[fb + idx[2]];
  float f2y = w0 * flow1[fb + NPTS + idx[0]]     + w1 * flow1[fb + NPTS + idx[1]]     + w2 * flow1[fb + NPTS + idx[2]];
  float f2z = w0 * flow1[fb + 2 * NPTS + idx[0]] + w1 * flow1[fb + 2 * NPTS + idx[1]] + w2 * flow1[fb + 2 * NPTS + idx[2]];
  float wx = q.x - f2x, wy = q.y - f2y, wz = q.z - f2z;
  out1[fb + n] = wx;
  out1[fb + NPTS + n] = wy;
  out1[fb + 2 * NPTS + n] = wz;
  C[qg] = make_float4(wx, wy, wz, 0.f);
}

// ---------------- gather + MLP(67->128->64) + leaky + max over K (no spill: LB(256,1))
__global__ void __launch_bounds__(256, 1) k_mlp(const int* __restrict__ Didx, const float4* __restrict__ C,
                                                const float4* __restrict__ Bq, const float* __restrict__ F,
                                                const float* __restrict__ W1p, const float* __restrict__ b1,
                                                const float* __restrict__ W2, const float* __restrict__ b2,
                                                float* __restrict__ out0) {
  int gid = blockIdx.x * 256 + threadIdx.x;   // 262144 threads
  int q = gid >> 4, k = gid & 15;
  int b = q >> 13, n = q & (NPTS - 1);
  int idx = Didx[q * KNN + k];
  float4 wp = C[b * NPTS + idx];
  float4 qp = Bq[q];
  float4 xq[17];
  xq[0] = make_float4(wp.x - qp.x, wp.y - qp.y, wp.z - qp.z, 0.f);
  const float4* fp = (const float4*)(F + ((size_t)(b * NPTS + idx)) * DF);
  {
    float4 v0 = fp[0];
    xq[0].w = v0.x;
#pragma unroll
    for (int j = 1; j < 16; ++j) {
      float4 v = fp[j];
      float4 pv = fp[j - 1];
      xq[j] = make_float4(pv.y, pv.z, pv.w, v.x);
    }
    float4 vl = fp[15];
    xq[16] = make_float4(vl.y, vl.z, vl.w, 0.f);
  }
  const float4* W14 = (const float4*)W1p;   // rows of 17 float4
  const float4* W24 = (const float4*)W2;    // rows of 32 float4
  float acc[OUTC];
#pragma unroll
  for (int o = 0; o < OUTC; ++o) acc[o] = b2[o];
  for (int ht = 0; ht < HID / 16; ++ht) {
    float h1t[16];
#pragma unroll
    for (int hh = 0; hh < 16; ++hh) {
      int h = ht * 16 + hh;
      const float4* wr = W14 + h * 17;
      float a = b1[h];
#pragma unroll
      for (int j = 0; j < 17; ++j) {
        float4 wv = wr[j];
        float4 xv = xq[j];
        a = fmaf(xv.x, wv.x, a);
        a = fmaf(xv.y, wv.y, a);
        a = fmaf(xv.z, wv.z, a);
        a = fmaf(xv.w, wv.w, a);
      }
      h1t[hh] = a >= 0.f ? a : 0.1f * a;
    }
#pragma unroll
    for (int o = 0; o < OUTC; ++o) {
      const float4* wr = W24 + o * 32 + ht * 4;
      float a = acc[o];
#pragma unroll
      for (int j = 0; j < 4; ++j) {
        float4 wv = wr[j];
        a = fmaf(h1t[4 * j + 0], wv.x, a);
        a = fmaf(h1t[4 * j + 1], wv.y, a);
        a = fmaf(h1t[4 * j + 2], wv.z, a);
        a = fmaf(h1t[4 * j + 3], wv.w, a);
      }
      acc[o] = a;
    }
  }
  int obase = (b * OUTC) * NPTS + n;
#pragma unroll
  for (int o = 0; o < OUTC; ++o) {
    float a = acc[o];
    a = a >= 0.f ? a : 0.1f * a;
    float m = a;
    m = fmaxf(m, __shfl_xor(m, 1));
    m = fmaxf(m, __shfl_xor(m, 2));
    m = fmaxf(m, __shfl_xor(m, 4));
    m = fmaxf(m, __shfl_xor(m, 8));
    if (k == 0) out0[obase + o * NPTS] = m;
  }
}

extern "C" void kernel_launch(void* const* d_in, const int* in_sizes, int n_in,
                              void* d_out, int out_size, void* d_ws, size_t ws_size,
                              hipStream_t stream) {
  const float* xyz1  = (const float*)d_in[0];
  const float* xyz2  = (const float*)d_in[1];
  const float* flow1 = (const float*)d_in[2];
  const float* feat2 = (const float*)d_in[3];
  const float* W1    = (const float*)d_in[4];
  const float* b1    = (const float*)d_in[5];
  const float* W2    = (const float*)d_in[6];
  const float* b2    = (const float*)d_in[7];
  float* out0 = (float*)d_out;
  float* out1 = out0 + (size_t)NB * OUTC * NPTS;

  float* w = (float*)d_ws;
  float4* A    = (float4*)(w);             // 65536 floats
  float4* Bq   = (float4*)(w + 65536);
  float4* Qx   = (float4*)(w + 131072);
  float4* Cw   = (float4*)(w + 196608);
  float*  F    = w + 262144;               // 1048576 floats
  float*  W1p  = w + 1310720;              // 8704 floats (pad to 16384)
  int*    idx3 = (int*)(w + 1327104);      // 49152 ints
  int*    Didx = (int*)(w + 1376256);      // 262144 ints

  k_prep<<<64, 256, 0, stream>>>(xyz1, xyz2, flow1, A, Bq, Qx);
  k_feat_T<<<dim3(128, 2), 256, 0, stream>>>(feat2, F);
  k_padw1<<<34, 256, 0, stream>>>(W1, W1p);
  k_knn_wave<3><<<2048, 256, 0, stream>>>(A, Qx, idx3);
  k_warp_finish<<<64, 256, 0, stream>>>(idx3, A, Qx, flow1, out1, Cw);
  k_knn_wave<16><<<2048, 256, 0, stream>>>(Cw, Bq, Didx);
  k_mlp<<<1024, 256, 0, stream>>>(Didx, Cw, Bq, F, W1p, b1, W2, b2, out0);
}

// Round 7
// 529.611 us; speedup vs baseline: 3.9772x; 2.1650x over previous
//
#include <hip/hip_runtime.h>
#include <math.h>

#define NPTS 8192
#define NB 2
#define DF 64
#define HID 128
#define OUTC 64
#define KNN 16

// ---------------- prep: pack points as float4(x,y,z,0)
__global__ void k_prep(const float* __restrict__ xyz1, const float* __restrict__ xyz2,
                       const float* __restrict__ flow1,
                       float4* __restrict__ A, float4* __restrict__ Bq, float4* __restrict__ Qx) {
  int t = blockIdx.x * 256 + threadIdx.x;      // 0..16383
  int b = t >> 13, n = t & (NPTS - 1);
  size_t base = (size_t)b * 3 * NPTS + n;
  float x1 = xyz1[base], y1 = xyz1[base + NPTS], z1 = xyz1[base + 2 * NPTS];
  float fx = flow1[base], fy = flow1[base + NPTS], fz = flow1[base + 2 * NPTS];
  float sx = x1 + fx, sy = y1 + fy, sz = z1 + fz;
  A[t]  = make_float4(sx, sy, sz, 0.f);
  Bq[t] = make_float4(x1, y1, z1, 0.f);
  float x2 = xyz2[base], y2 = xyz2[base + NPTS], z2 = xyz2[base + 2 * NPTS];
  Qx[t] = make_float4(x2, y2, z2, 0.f);
}

// ---------------- feat2 [B,D,N] -> F [B,N,D]
__global__ void k_feat_T(const float* __restrict__ feat2, float* __restrict__ F) {
  __shared__ float t[64][65];
  int b = blockIdx.y;
  int n0 = blockIdx.x * 64;
  int l = threadIdx.x & 63, w = threadIdx.x >> 6;
#pragma unroll
  for (int it = 0; it < 16; ++it) {
    int dd = w + it * 4;
    t[dd][l] = feat2[((size_t)b * DF + dd) * NPTS + n0 + l];
  }
  __syncthreads();
#pragma unroll
  for (int it = 0; it < 16; ++it) {
    int nn = w + it * 4;
    F[((size_t)b * NPTS + n0 + nn) * DF + l] = t[l][nn];
  }
}

// ---------------- Hfeat[pt][h] = b1[h] + sum_c F[pt][c] * W1[h][3+c]
// (feat-dependent part of layer 1, shared by all 16 neighbors that gather pt)
// thread <-> (pt, h); wave = 64 h of one pt -> F row is wave-uniform (s_load)
__global__ void k_hfeat(const float* __restrict__ F, const float* __restrict__ W1,
                        const float* __restrict__ b1, float* __restrict__ Hfeat) {
  int tid = threadIdx.x;
  int pt = blockIdx.x * 2 + (tid >> 7);     // 2 points per 256-thread block
  int h = tid & 127;
  const float* fr = F + (size_t)pt * DF;
  const float* wr = W1 + h * 67 + 3;
  float a = b1[h];
#pragma unroll
  for (int c = 0; c < DF; ++c) a = fmaf(fr[c], wr[c], a);
  Hfeat[(size_t)pt * HID + h] = a;          // NO leaky here (xyz part added later)
}

// ---------------- wave-per-2-queries exact KNN, lane-distributed sorted top-K
// List lives across lanes: lane l holds the l-th smallest (d, idx) seen so far.
// Candidates filtered by exact (d,idx) compare vs the K-th element; inserts are
// wave-wide shuffle shifts (processed in ascending point index for tie order).
template<int K>
__global__ void __launch_bounds__(256) k_knn_wave(const float4* __restrict__ db,
                                                  const float4* __restrict__ qry,
                                                  int* __restrict__ outIdx) {
  int wid = (blockIdx.x * 256 + threadIdx.x) >> 6;   // 0..8191
  int lane = threadIdx.x & 63;
  int b = wid >> 12;                                  // batch
  int q0 = wid * 2, q1 = wid * 2 + 1;
  float4 Q0 = qry[q0], Q1 = qry[q1];
  const float4* base = db + (size_t)b * NPTS;

  float ld0 = __builtin_inff(), ld1 = __builtin_inff();
  int   li0 = 0x7fffffff,       li1 = 0x7fffffff;
  float cap0 = __builtin_inff(), cap1 = __builtin_inff();
  int   ci0 = 0x7fffffff,        ci1 = 0x7fffffff;

  for (int t = 0; t < NPTS / 64; ++t) {
    int j = t * 64 + lane;
    float4 p = base[j];
    float ax = Q0.x - p.x, ay = Q0.y - p.y, az = Q0.z - p.z;
    float d0 = fmaf(ax, ax, fmaf(ay, ay, az * az));
    float bx = Q1.x - p.x, by = Q1.y - p.y, bz = Q1.z - p.z;
    float d1 = fmaf(bx, bx, fmaf(by, by, bz * bz));

    unsigned long long m0 = __ballot((d0 < cap0) || (d0 == cap0 && j < ci0));
    if (m0) {
      do {
        int c = __ffsll(m0) - 1; m0 &= m0 - 1;
        float bd = __shfl(d0, c); int bi = t * 64 + c;
        bool pred = (ld0 > bd) || (ld0 == bd && li0 > bi);
        float sld = __shfl_up(ld0, 1);
        int   sli = __shfl_up(li0, 1);
        int   ppr = __shfl_up((int)pred, 1);
        bool  pp = (lane > 0) && ppr;
        ld0 = pred ? (pp ? sld : bd) : ld0;
        li0 = pred ? (pp ? sli : bi) : li0;
      } while (m0);
      cap0 = __shfl(ld0, K - 1); ci0 = __shfl(li0, K - 1);
    }
    unsigned long long m1 = __ballot((d1 < cap1) || (d1 == cap1 && j < ci1));
    if (m1) {
      do {
        int c = __ffsll(m1) - 1; m1 &= m1 - 1;
        float bd = __shfl(d1, c); int bi = t * 64 + c;
        bool pred = (ld1 > bd) || (ld1 == bd && li1 > bi);
        float sld = __shfl_up(ld1, 1);
        int   sli = __shfl_up(li1, 1);
        int   ppr = __shfl_up((int)pred, 1);
        bool  pp = (lane > 0) && ppr;
        ld1 = pred ? (pp ? sld : bd) : ld1;
        li1 = pred ? (pp ? sli : bi) : li1;
      } while (m1);
      cap1 = __shfl(ld1, K - 1); ci1 = __shfl(li1, K - 1);
    }
  }
  if (lane < K) {
    outIdx[q0 * K + lane] = li0;
    outIdx[q1 * K + lane] = li1;
  }
}

// ---------------- 3-NN inverse-distance warp interpolation (indices precomputed)
__global__ void k_warp_finish(const int* __restrict__ idx3,
                              const float4* __restrict__ A, const float4* __restrict__ Qx,
                              const float* __restrict__ flow1, float* __restrict__ out1,
                              float4* __restrict__ C) {
  int qg = blockIdx.x * 256 + threadIdx.x;
  int b = qg >> 13, n = qg & (NPTS - 1);
  int idx[3];
#pragma unroll
  for (int r = 0; r < 3; ++r) idx[r] = idx3[qg * 3 + r];
  float4 q = Qx[qg];
  float ivd[3];
  float s = 0.f;
#pragma unroll
  for (int r = 0; r < 3; ++r) {
    float4 p = A[b * NPTS + idx[r]];
    float gx = p.x - q.x, gy = p.y - q.y, gz = p.z - q.z;
    float dist = sqrtf(gx * gx + gy * gy + gz * gz);
    dist = fmaxf(dist, 1e-10f);
    ivd[r] = 1.0f / dist;
    s += ivd[r];
  }
  float w0 = ivd[0] / s, w1 = ivd[1] / s, w2 = ivd[2] / s;
  size_t fb = (size_t)b * 3 * NPTS;
  float f2x = w0 * flow1[fb + idx[0]]            + w1 * flow1[fb + idx[1]]            + w2 * flow1[fb + idx[2]];
  float f2y = w0 * flow1[fb + NPTS + idx[0]]     + w1 * flow1[fb + NPTS + idx[1]]     + w2 * flow1[fb + NPTS + idx[2]];
  float f2z = w0 * flow1[fb + 2 * NPTS + idx[0]] + w1 * flow1[fb + 2 * NPTS + idx[1]] + w2 * flow1[fb + 2 * NPTS + idx[2]];
  float wx = q.x - f2x, wy = q.y - f2y, wz = q.z - f2z;
  out1[fb + n] = wx;
  out1[fb + NPTS + n] = wy;
  out1[fb + 2 * NPTS + n] = wz;
  C[qg] = make_float4(wx, wy, wz, 0.f);
}

// ---------------- per-(q,k): h1 = Hfeat[idx] + W1xyz·dxyz -> leaky -> W2 -> leaky -> max_k
// acc[64]+h1t[16]+dxyz ≈ 95 VGPR: no spill. Weight reads wave-uniform -> SGPR s_loads.
__global__ void __launch_bounds__(256) k_mlp2(const int* __restrict__ Didx, const float4* __restrict__ C,
                                              const float4* __restrict__ Bq, const float* __restrict__ Hfeat,
                                              const float* __restrict__ W1, const float* __restrict__ W2,
                                              const float* __restrict__ b2, float* __restrict__ out0) {
  int gid = blockIdx.x * 256 + threadIdx.x;   // 262144 threads
  int q = gid >> 4, k = gid & 15;
  int b = q >> 13, n = q & (NPTS - 1);
  int idx = Didx[q * KNN + k];
  float4 wp = C[b * NPTS + idx];
  float4 qp = Bq[q];
  float dx = wp.x - qp.x, dy = wp.y - qp.y, dz = wp.z - qp.z;
  const float* hf = Hfeat + ((size_t)(b * NPTS + idx)) * HID;

  float acc[OUTC];
#pragma unroll
  for (int o = 0; o < OUTC; ++o) acc[o] = b2[o];

  for (int ht = 0; ht < HID / 16; ++ht) {
    float h1t[16];
#pragma unroll
    for (int j = 0; j < 4; ++j) {
      float4 v = *(const float4*)(hf + ht * 16 + j * 4);
      h1t[4 * j + 0] = v.x; h1t[4 * j + 1] = v.y; h1t[4 * j + 2] = v.z; h1t[4 * j + 3] = v.w;
    }
#pragma unroll
    for (int hh = 0; hh < 16; ++hh) {
      int h = ht * 16 + hh;
      float a = h1t[hh];
      a = fmaf(dx, W1[h * 67 + 0], a);
      a = fmaf(dy, W1[h * 67 + 1], a);
      a = fmaf(dz, W1[h * 67 + 2], a);
      h1t[hh] = a >= 0.f ? a : 0.1f * a;
    }
#pragma unroll
    for (int o = 0; o < OUTC; ++o) {
      const float* wr = W2 + o * HID + ht * 16;
      float a = acc[o];
#pragma unroll
      for (int hh = 0; hh < 16; ++hh) a = fmaf(h1t[hh], wr[hh], a);
      acc[o] = a;
    }
  }
  int obase = (b * OUTC) * NPTS + n;
#pragma unroll
  for (int o = 0; o < OUTC; ++o) {
    float a = acc[o];
    a = a >= 0.f ? a : 0.1f * a;
    float m = a;
    m = fmaxf(m, __shfl_xor(m, 1));
    m = fmaxf(m, __shfl_xor(m, 2));
    m = fmaxf(m, __shfl_xor(m, 4));
    m = fmaxf(m, __shfl_xor(m, 8));
    if (k == 0) out0[obase + o * NPTS] = m;
  }
}

extern "C" void kernel_launch(void* const* d_in, const int* in_sizes, int n_in,
                              void* d_out, int out_size, void* d_ws, size_t ws_size,
                              hipStream_t stream) {
  const float* xyz1  = (const float*)d_in[0];
  const float* xyz2  = (const float*)d_in[1];
  const float* flow1 = (const float*)d_in[2];
  const float* feat2 = (const float*)d_in[3];
  const float* W1    = (const float*)d_in[4];
  const float* b1    = (const float*)d_in[5];
  const float* W2    = (const float*)d_in[6];
  const float* b2    = (const float*)d_in[7];
  float* out0 = (float*)d_out;
  float* out1 = out0 + (size_t)NB * OUTC * NPTS;

  float* w = (float*)d_ws;
  float4* A     = (float4*)(w);             // 65536 floats
  float4* Bq    = (float4*)(w + 65536);
  float4* Qx    = (float4*)(w + 131072);
  float4* Cw    = (float4*)(w + 196608);
  float*  F     = w + 262144;               // 1048576 floats
  float*  Hfeat = w + 1310720;              // 2097152 floats (8 MB)
  int*    idx3  = (int*)(w + 3407872);      // 49152 ints
  int*    Didx  = (int*)(w + 3457024);      // 262144 ints

  k_prep<<<64, 256, 0, stream>>>(xyz1, xyz2, flow1, A, Bq, Qx);
  k_feat_T<<<dim3(128, 2), 256, 0, stream>>>(feat2, F);
  k_hfeat<<<NB * NPTS / 2, 256, 0, stream>>>(F, W1, b1, Hfeat);
  k_knn_wave<3><<<2048, 256, 0, stream>>>(A, Qx, idx3);
  k_warp_finish<<<64, 256, 0, stream>>>(idx3, A, Qx, flow1, out1, Cw);
  k_knn_wave<16><<<2048, 256, 0, stream>>>(Cw, Bq, Didx);
  k_mlp2<<<1024, 256, 0, stream>>>(Didx, Cw, Bq, Hfeat, W1, W2, b2, out0);
}